// Round 11
// baseline (1101.298 us; speedup 1.0000x reference)
//
#include <hip/hip_runtime.h>
#include <math.h>
#include <stdint.h>

#define E_N 19
#define H_N 32
#define T_N 2048
#define B_N 64
#define G_N 128      // 4*H gate rows per chain
#define XCHUNK 64    // timesteps staged per LDS round
#define LOG2E 1.4426950408889634f

typedef _Float16 half2_t __attribute__((ext_vector_type(2)));
typedef __fp16   fp16v2  __attribute__((ext_vector_type(2)));

__device__ __forceinline__ float sigm_rcp(float e) {  // 1/(1+e)
    return __builtin_amdgcn_rcpf(1.0f + e);
}

// Pack (h_this, h_neighbor) into fp16x2 using quad_perm [1,0,3,2] (lane^1 swap,
// direction-unambiguous) + cvt_pkrtz. Valid pairs land in even lanes.
__device__ __forceinline__ uint32_t pack_h_pair(float h) {
    const int hn = __builtin_amdgcn_mov_dpp(__float_as_int(h), 0xB1, 0xF, 0xF, false);
    const fp16v2 pk = __builtin_amdgcn_cvt_pkrtz(h, __int_as_float(hn));
    return __builtin_bit_cast(uint32_t, pk);
}

// One WAVE per chain (b, e, dir). h broadcast WITHOUT LDS storage:
// 16x ds_bpermute_b32 pulls packed fp16 h-pairs straight from half1's VGPRs
// (one pipelined DS trip), replacing R8's write->read (two dependent trips).
// Lane pairing: half0 lane j owns rows i_j, g_j (ig local); half1 owns f_j, o_j
// (c/h update local after one shfl_xor(ig,32)).
__global__ __launch_bounds__(64)
__attribute__((amdgpu_waves_per_eu(3, 3)))
void lstm_chain_kernel(
    const float* __restrict__ x,     // [B, T, E]
    const float* __restrict__ w_ih,  // [E, 2, 4H]
    const float* __restrict__ w_hh,  // [E, 2, 4H, H]
    const float* __restrict__ b_ih,  // [E, 2, 4H]
    const float* __restrict__ b_hh,  // [E, 2, 4H]
    float* __restrict__ hT)          // [B, E, 2, H]
{
    const int lane  = threadIdx.x;
    const int chain = blockIdx.x;            // b*(E*2) + e*2 + d
    const int b  = chain / (E_N * 2);
    const int ed = chain - b * (E_N * 2);
    const int e  = ed >> 1;
    const int d  = ed & 1;
    const int j    = lane & 31;
    const int half = lane >> 5;

    const int r1 = j + 32 * half;        // i_j (half0) or f_j (half1) -> sigmoid
    const int r2 = j + 64 + 32 * half;   // g_j (half0, tanh) or o_j (half1, sigmoid)

    // ---- load fp32 weights, quantize to packed fp16 pairs (16+16 VGPRs) ----
    const float* wr1 = w_hh + ((size_t)ed * G_N + r1) * H_N;
    const float* wr2 = w_hh + ((size_t)ed * G_N + r2) * H_N;
    uint32_t w1p[16], w2p[16];
    #pragma unroll
    for (int m = 0; m < 16; ++m) {
        float2 v1 = ((const float2*)wr1)[m];
        float2 v2 = ((const float2*)wr2)[m];
        half2_t p1 = { (_Float16)v1.x, (_Float16)v1.y };
        half2_t p2 = { (_Float16)v2.x, (_Float16)v2.y };
        w1p[m] = __builtin_bit_cast(uint32_t, p1);
        w2p[m] = __builtin_bit_cast(uint32_t, p2);
    }

    const float wih1  = w_ih[(size_t)ed * G_N + r1];
    const float wih2  = w_ih[(size_t)ed * G_N + r2];
    const float bias1 = b_ih[(size_t)ed * G_N + r1] + b_hh[(size_t)ed * G_N + r1];
    const float bias2 = b_ih[(size_t)ed * G_N + r2] + b_hh[(size_t)ed * G_N + r2];

    // act2: half0 -> tanh(g) = 2*sigm(2g)-1 ; half1 -> sigmoid(o)
    const float K2 = half ? (-LOG2E) : (-2.0f * LOG2E);
    const float A2 = half ?  1.0f :  2.0f;
    const float B2 = half ?  0.0f : -1.0f;

    __shared__ float xbuf[XCHUNK];

    float c = 0.0f;      // valid on half1
    float h = 0.0f;      // valid on half1
    uint32_t pk = 0u;    // packed (h_2m, h_2m+1) pairs, valid in even half1 lanes

    const float* xbase = x + (size_t)b * T_N * E_N + e;

    for (int t0 = 0; t0 < T_N; t0 += XCHUNK) {
        // PIN: keep the 32 packed weight regs live across the inner loop (no-op).
        #pragma unroll
        for (int m = 0; m < 16; ++m) {
            asm volatile("" : "+v"(w1p[m]), "+v"(w2p[m]));
        }

        // stage 64 timesteps into LDS, one per lane (reversed time for d==1)
        const int tt    = t0 + lane;
        const int tphys = d ? (T_N - 1 - tt) : tt;
        xbuf[lane] = xbase[(size_t)tphys * E_N];

        #pragma unroll 1
        for (int tl = 0; tl < XCHUNK; ++tl) {
            // h broadcast: 16 bpermutes from even half1 lanes (one DS trip)
            uint32_t hp[16];
            #pragma unroll
            for (int m = 0; m < 16; ++m) {
                hp[m] = (uint32_t)__builtin_amdgcn_ds_bpermute(4 * (32 + 2 * m), (int)pk);
            }
            const float sx = xbuf[tl];   // uniform LDS read, overlaps bpermutes

            // 8 chains of 4 dot2 (short dependency chains)
            float s10 = bias1, s11 = 0.0f, s12 = 0.0f, s13 = 0.0f;
            float s20 = bias2, s21 = 0.0f, s22 = 0.0f, s23 = 0.0f;
            #pragma unroll
            for (int m = 0; m < 4; ++m) {
                s10 = __builtin_amdgcn_fdot2(__builtin_bit_cast(half2_t, hp[m]),
                                             __builtin_bit_cast(half2_t, w1p[m]),    s10, false);
                s11 = __builtin_amdgcn_fdot2(__builtin_bit_cast(half2_t, hp[m+4]),
                                             __builtin_bit_cast(half2_t, w1p[m+4]),  s11, false);
                s12 = __builtin_amdgcn_fdot2(__builtin_bit_cast(half2_t, hp[m+8]),
                                             __builtin_bit_cast(half2_t, w1p[m+8]),  s12, false);
                s13 = __builtin_amdgcn_fdot2(__builtin_bit_cast(half2_t, hp[m+12]),
                                             __builtin_bit_cast(half2_t, w1p[m+12]), s13, false);
                s20 = __builtin_amdgcn_fdot2(__builtin_bit_cast(half2_t, hp[m]),
                                             __builtin_bit_cast(half2_t, w2p[m]),    s20, false);
                s21 = __builtin_amdgcn_fdot2(__builtin_bit_cast(half2_t, hp[m+4]),
                                             __builtin_bit_cast(half2_t, w2p[m+4]),  s21, false);
                s22 = __builtin_amdgcn_fdot2(__builtin_bit_cast(half2_t, hp[m+8]),
                                             __builtin_bit_cast(half2_t, w2p[m+8]),  s22, false);
                s23 = __builtin_amdgcn_fdot2(__builtin_bit_cast(half2_t, hp[m+12]),
                                             __builtin_bit_cast(half2_t, w2p[m+12]), s23, false);
            }
            const float g1 = fmaf(sx, wih1, (s10 + s11) + (s12 + s13));
            const float g2 = fmaf(sx, wih2, (s20 + s21) + (s22 + s23));

            // act1: sigmoid on both halves (i_j / f_j)
            const float act1 = sigm_rcp(__builtin_amdgcn_exp2f(g1 * (-LOG2E)));
            // act2: tanh (half0: g_j) / sigmoid (half1: o_j)
            const float act2 = fmaf(A2, sigm_rcp(__builtin_amdgcn_exp2f(g2 * K2)), B2);

            const float ig  = act1 * act2;           // half0: i*g (valid); half1: f*o (junk)
            const float igx = __shfl_xor(ig, 32);    // half1 receives i*g   [one DS trip]

            // valid on half1 only (half0 computes garbage on same instructions)
            c = fmaf(act1, c, igx);                                   // f*c + i*g
            const float tc = fmaf(2.0f, sigm_rcp(
                __builtin_amdgcn_exp2f(c * (-2.0f * LOG2E))), -1.0f); // tanh(c)
            h = act2 * tc;                                            // o * tanh(c)

            // publish h: DPP neighbor-swap + pack (pure VALU, no LDS)
            pk = pack_h_pair(h);
        }
    }

    if (half) {
        hT[((size_t)(b * E_N + e) * 2 + d) * H_N + j] = h;
    }
}

// LayerNorm over 64 feats per (b,e), mean over e, FC -> out[b]. One wave per b.
__global__ __launch_bounds__(64) void head_kernel(
    const float* __restrict__ hT,      // [B, E, 64]
    const float* __restrict__ ln_gamma,// [E, 64]
    const float* __restrict__ ln_beta, // [E, 64]
    const float* __restrict__ fc_w,    // [64]
    const float* __restrict__ fc_b,    // [1]
    float* __restrict__ out)           // [B]
{
    const int b = blockIdx.x;
    const int f = threadIdx.x; // 0..63

    float acc = 0.0f;
    for (int e = 0; e < E_N; ++e) {
        const float v = hT[(size_t)(b * E_N + e) * 64 + f];
        float s = v, s2 = v * v;
        #pragma unroll
        for (int off = 32; off > 0; off >>= 1) {
            s  += __shfl_xor(s,  off);
            s2 += __shfl_xor(s2, off);
        }
        const float mean = s * (1.0f / 64.0f);
        const float var  = s2 * (1.0f / 64.0f) - mean * mean;
        const float inv  = rsqrtf(var + 1e-5f);
        acc += (v - mean) * inv * ln_gamma[e * 64 + f] + ln_beta[e * 64 + f];
    }
    float contrib = (acc * (1.0f / (float)E_N)) * fc_w[f];
    #pragma unroll
    for (int off = 32; off > 0; off >>= 1) contrib += __shfl_xor(contrib, off);
    if (f == 0) out[b] = contrib + fc_b[0];
}

extern "C" void kernel_launch(void* const* d_in, const int* in_sizes, int n_in,
                              void* d_out, int out_size, void* d_ws, size_t ws_size,
                              hipStream_t stream) {
    const float* x        = (const float*)d_in[0];
    const float* w_ih     = (const float*)d_in[1];
    const float* w_hh     = (const float*)d_in[2];
    const float* b_ih     = (const float*)d_in[3];
    const float* b_hh     = (const float*)d_in[4];
    const float* ln_gamma = (const float*)d_in[5];
    const float* ln_beta  = (const float*)d_in[6];
    const float* fc_w     = (const float*)d_in[7];
    const float* fc_b     = (const float*)d_in[8];
    float* out = (float*)d_out;
    float* hT  = (float*)d_ws;  // B*E*2*H floats

    lstm_chain_kernel<<<B_N * E_N * 2, 64, 0, stream>>>(x, w_ih, w_hh, b_ih, b_hh, hT);
    head_kernel<<<B_N, 64, 0, stream>>>(hT, ln_gamma, ln_beta, fc_w, fc_b, out);
}